// Round 1
// 957.555 us; speedup vs baseline: 1.0976x; 1.0976x over previous
//
#include <hip/hip_runtime.h>
#include <stdint.h>

#define ALPHA 0.05f
constexpr int B_   = 8;
constexpr int CIN  = 32;
constexpr int NN   = 1024;
constexpr int CC   = 16;
constexpr int HID_ = 20;
constexpr int COUT = 32;
constexpr int PAIRS = B_ * CC;   // 128

typedef __attribute__((ext_vector_type(8))) short bf8;   // 8 bf16 in 4 VGPRs
typedef __attribute__((ext_vector_type(4))) float f4;

__device__ inline unsigned short f2bf(float x) {
    union { float f; uint32_t u; } v; v.f = x;
    uint32_t u = v.u;
    u += 0x7fffu + ((u >> 16) & 1u);   // round-to-nearest-even
    return (unsigned short)(u >> 16);
}

// ---------------------------------------------------------------------------
// K0: swizzle-convert adj f32 -> bf16 in MFMA A-fragment order.
//     Output tile (pair, mb, kb) = rows mb*16..+15, cols kb*32..+31, stored as
//     1 KB contiguous: ushort index = lane*8 + e, lane=(quad<<4)|ml holds
//     row ml, cols quad*8+e  (exactly the 16x16x32 A-frag mapping).
//     Block: 64 rows x 256 cols; coalesced f32 read -> LDS -> coalesced write.
// ---------------------------------------------------------------------------
constexpr int CSTR = 268;   // LDS row stride in bf16 (536 B: 8B-aligned, word%32=6)

__global__ __launch_bounds__(256) void k_conv(const float* __restrict__ adj,
                                              unsigned short* __restrict__ Asw) {
    int pair = blockIdx.y;
    int rb = blockIdx.x >> 2;      // row-block of 64   (0..15)
    int cb = blockIdx.x & 3;       // col-block of 256  (0..3)
    __shared__ unsigned short T[64 * CSTR];   // 33.5 KB
    int t = threadIdx.x;

    const float* src = adj + ((size_t)pair * NN + rb * 64) * NN + cb * 256;
    #pragma unroll
    for (int j = 0; j < 16; j++) {
        int idx = j * 256 + t;            // 0..4095 float4s, row-major
        int row = idx >> 6, c4 = idx & 63;
        float4 v = *(const float4*)(src + (size_t)row * NN + c4 * 4);
        ushort4 w;
        w.x = f2bf(v.x); w.y = f2bf(v.y); w.z = f2bf(v.z); w.w = f2bf(v.w);
        *(ushort4*)&T[row * CSTR + c4 * 4] = w;
    }
    __syncthreads();

    int lane = t & 63, wave = t >> 6;
    int ml = lane & 15, quad = lane >> 4;
    // wave w owns mb = rb*4 + w; per kb, lane reads its 8 frag elems from LDS
    unsigned short* dst = Asw +
        (((size_t)pair * 64 + rb * 4 + wave) * 32 + cb * 8) * 512 + lane * 8;
    const unsigned short* srcT = &T[(wave * 16 + ml) * CSTR + quad * 8];
    #pragma unroll
    for (int kb = 0; kb < 8; kb++) {
        uint2 lo = *(const uint2*)(srcT + kb * 32);
        uint2 hi = *(const uint2*)(srcT + kb * 32 + 4);
        uint4 o; o.x = lo.x; o.y = lo.y; o.z = hi.x; o.w = hi.y;
        *(uint4*)(dst + (size_t)kb * 512) = o;    // 1 KB contiguous per wave
    }
}

// ---------------------------------------------------------------------------
// K1: h0[pair][n][l] = sum_i x[b][i][n][c] * W_start[i][l] + b_start[l]
// ---------------------------------------------------------------------------
__global__ __launch_bounds__(256) void k_h0(const float* __restrict__ x,
                                            const float* __restrict__ Ws,
                                            const float* __restrict__ bs,
                                            float* __restrict__ h0) {
    int b = blockIdx.y, n0 = blockIdx.x * 16;
    __shared__ float xs[CIN * 16 * CC];   // [i][nl][c], 32 KB
    __shared__ float WsS[CIN * HID_];
    __shared__ float bsS[HID_];
    int t = threadIdx.x;

    #pragma unroll
    for (int j = 0; j < 8; j++) {
        int idx = t + j * 256;            // 0..2047
        int i = idx >> 6, f = idx & 63;
        ((float4*)xs)[idx] =
            ((const float4*)(x + ((size_t)(b * CIN + i) * NN + n0) * CC))[f];
    }
    for (int j = t; j < CIN * HID_; j += 256) WsS[j] = Ws[j];
    if (t < HID_) bsS[t] = bs[t];
    __syncthreads();

    int c = t & 15, nl = t >> 4;
    float acc[HID_];
    #pragma unroll
    for (int l = 0; l < HID_; l++) acc[l] = bsS[l];
    for (int i = 0; i < CIN; i++) {
        float xv = xs[i * 256 + nl * 16 + c];
        #pragma unroll
        for (int l = 0; l < HID_; l++) acc[l] += xv * WsS[i * HID_ + l];
    }
    float* dst = h0 + ((size_t)(b * CC + c) * NN + (n0 + nl)) * HID_;
    #pragma unroll
    for (int l = 0; l < HID_; l++) dst[l] = acc[l];
}

// ---------------------------------------------------------------------------
// P: one propagation pass — barrier-free K-loop over pre-swizzled bf16 A.
//    B^T (32 x 1024 bf16: rows 0..19 = h^T, row 20 = ones, 21..31 = 0) staged
//    once in LDS. A-frags are contiguous 1 KB tile loads (no conversion).
//    s = rowsum (col 20) + 1 ; h_out = ALPHA*h0 + (1-ALPHA)*(u + h_in)/s
//    grid: (4 m-tiles of 256, 128 pairs), block 512 (8 waves).
// ---------------------------------------------------------------------------
constexpr int BSTR = 1032;   // LDS row stride in bf16 (+8 pad)

__global__ __launch_bounds__(512, 4) void k_prop(
        const unsigned short* __restrict__ Asw,  // bf16 fragment-ordered A
        const float* __restrict__ h_in,   // f32: B source AND identity add
        const float* __restrict__ h0,     // f32: alpha mix
        float* __restrict__ h_out) {
    int pair = blockIdx.y;
    int m0 = blockIdx.x * 256;
    __shared__ unsigned short Ht[32 * BSTR];   // 66 KB
    int t = threadIdx.x;
    int lane = t & 63, wave = t >> 6;
    int ml = lane & 15, quad = lane >> 4;

    // ---- stage B^T (once) ----
    const float* hp = h_in + (size_t)pair * NN * HID_;
    for (int k = t; k < NN; k += 512) {
        float4 v0 = *(const float4*)(hp + (size_t)k * HID_ + 0);
        float4 v1 = *(const float4*)(hp + (size_t)k * HID_ + 4);
        float4 v2 = *(const float4*)(hp + (size_t)k * HID_ + 8);
        float4 v3 = *(const float4*)(hp + (size_t)k * HID_ + 12);
        float4 v4 = *(const float4*)(hp + (size_t)k * HID_ + 16);
        float vv[20] = {v0.x, v0.y, v0.z, v0.w, v1.x, v1.y, v1.z, v1.w,
                        v2.x, v2.y, v2.z, v2.w, v3.x, v3.y, v3.z, v3.w,
                        v4.x, v4.y, v4.z, v4.w};
        #pragma unroll
        for (int l = 0; l < HID_; l++) Ht[l * BSTR + k] = f2bf(vv[l]);
    }
    {   // rows 20 (ones) and 21..31 (zeros), vectorized
        uint4 ones; ones.x = ones.y = ones.z = ones.w = 0x3F803F80u;
        uint4 zero; zero.x = zero.y = zero.z = zero.w = 0u;
        for (int idx = t; idx < 12 * (NN / 8); idx += 512) {
            int row = 20 + (idx >> 7), seg = idx & 127;
            *(uint4*)&Ht[row * BSTR + seg * 8] = (row == 20) ? ones : zero;
        }
    }
    __syncthreads();

    // ---- K-loop (no barriers) ----
    f4 acc[2][2];
    #pragma unroll
    for (int mt = 0; mt < 2; mt++)
        #pragma unroll
        for (int nt = 0; nt < 2; nt++)
            #pragma unroll
            for (int r = 0; r < 4; r++) acc[mt][nt][r] = 0.0f;

    // tile streams for this wave: mb0 = m0/16 + wave*2, mb1 = mb0+1
    const unsigned short* At0 = Asw +
        ((size_t)pair * 64 + blockIdx.x * 16 + wave * 2) * (32 * 512) + lane * 8;
    const unsigned short* At1 = At0 + 32 * 512;
    const int b0off = ml * BSTR + quad * 8;
    const int b1off = b0off + 16 * BSTR;

    bf8 cA0 = *(const bf8*)(At0);
    bf8 cA1 = *(const bf8*)(At1);
    bf8 cB0 = *(const bf8*)(At0 + 512);
    bf8 cB1 = *(const bf8*)(At1 + 512);

    #pragma unroll 1
    for (int ks = 0; ks < NN; ks += 64) {
        int kb = ks >> 5;
        int kn = (kb + 2 < 32) ? (kb + 2) : 0;   // wrap-guarded prefetch
        bf8 nA0 = *(const bf8*)(At0 + kn * 512);
        bf8 nA1 = *(const bf8*)(At1 + kn * 512);
        bf8 nB0 = *(const bf8*)(At0 + kn * 512 + 512);
        bf8 nB1 = *(const bf8*)(At1 + kn * 512 + 512);
        {
            bf8 b0 = *(const bf8*)&Ht[b0off + ks];
            bf8 b1 = *(const bf8*)&Ht[b1off + ks];
            acc[0][0] = __builtin_amdgcn_mfma_f32_16x16x32_bf16(cA0, b0, acc[0][0], 0, 0, 0);
            acc[0][1] = __builtin_amdgcn_mfma_f32_16x16x32_bf16(cA0, b1, acc[0][1], 0, 0, 0);
            acc[1][0] = __builtin_amdgcn_mfma_f32_16x16x32_bf16(cA1, b0, acc[1][0], 0, 0, 0);
            acc[1][1] = __builtin_amdgcn_mfma_f32_16x16x32_bf16(cA1, b1, acc[1][1], 0, 0, 0);
        }
        {
            bf8 b0 = *(const bf8*)&Ht[b0off + ks + 32];
            bf8 b1 = *(const bf8*)&Ht[b1off + ks + 32];
            acc[0][0] = __builtin_amdgcn_mfma_f32_16x16x32_bf16(cB0, b0, acc[0][0], 0, 0, 0);
            acc[0][1] = __builtin_amdgcn_mfma_f32_16x16x32_bf16(cB0, b1, acc[0][1], 0, 0, 0);
            acc[1][0] = __builtin_amdgcn_mfma_f32_16x16x32_bf16(cB1, b0, acc[1][0], 0, 0, 0);
            acc[1][1] = __builtin_amdgcn_mfma_f32_16x16x32_bf16(cB1, b1, acc[1][1], 0, 0, 0);
        }
        cA0 = nA0; cA1 = nA1; cB0 = nB0; cB1 = nB1;
    }

    // ---- epilogue: C/D layout col = lane&15 (+16*nt), row = quad*4 + reg ----
    #pragma unroll
    for (int mt = 0; mt < 2; mt++) {
        #pragma unroll
        for (int r = 0; r < 4; r++) {
            int row = m0 + wave * 32 + mt * 16 + quad * 4 + r;
            float s = __shfl(acc[mt][1][r], (quad << 4) + 4, 64) + 1.0f;
            float inv_s = (1.0f - ALPHA) / s;
            {
                size_t off = ((size_t)pair * NN + row) * HID_ + ml;
                h_out[off] = ALPHA * h0[off] + inv_s * (acc[mt][0][r] + h_in[off]);
            }
            if (ml < 4) {
                size_t off = ((size_t)pair * NN + row) * HID_ + 16 + ml;
                h_out[off] = ALPHA * h0[off] + inv_s * (acc[mt][1][r] + h_in[off]);
            }
        }
    }
}

// ---------------------------------------------------------------------------
// K3: out[pair][n][o] = sum_k [h0|h1|h2|h3][pair][n][k] * W_end[k][o] + b_end[o]
// ---------------------------------------------------------------------------
__global__ __launch_bounds__(256) void k_out(const float* __restrict__ h0,
                                             const float* __restrict__ h1,
                                             const float* __restrict__ h2,
                                             const float* __restrict__ h3,
                                             const float* __restrict__ We,
                                             const float* __restrict__ be,
                                             float* __restrict__ out) {
    int pair = blockIdx.y, n0 = blockIdx.x * 128;
    int t = threadIdx.x;
    __shared__ float WeT[32 * 84];   // WeT[o][k]
    __shared__ float beS[32];
    for (int idx = t; idx < 80 * 32; idx += 256) {
        int k = idx >> 5, o = idx & 31;
        WeT[o * 84 + k] = We[idx];
    }
    if (t < 32) beS[t] = be[t];
    __syncthreads();

    const float* hs[4] = {h0, h1, h2, h3};
    int og = t & 7, ng = t >> 3;
    float acc[4][4];
    #pragma unroll
    for (int r = 0; r < 4; r++)
        #pragma unroll
        for (int c = 0; c < 4; c++) acc[r][c] = beS[og + c * 8];

    #pragma unroll
    for (int src = 0; src < 4; src++) {
        const float* hp = hs[src] + ((size_t)pair * NN + n0 + ng) * HID_;
        #pragma unroll
        for (int j = 0; j < 5; j++) {
            float4 hv[4];
            #pragma unroll
            for (int r = 0; r < 4; r++)
                hv[r] = *(const float4*)(hp + (size_t)(r * 32) * HID_ + j * 4);
            #pragma unroll
            for (int c = 0; c < 4; c++) {
                float4 wv = *(const float4*)&WeT[(og + c * 8) * 84 + src * 20 + j * 4];
                #pragma unroll
                for (int r = 0; r < 4; r++)
                    acc[r][c] += hv[r].x * wv.x + hv[r].y * wv.y +
                                 hv[r].z * wv.z + hv[r].w * wv.w;
            }
        }
    }
    #pragma unroll
    for (int r = 0; r < 4; r++)
        #pragma unroll
        for (int c = 0; c < 4; c++)
            out[((size_t)pair * NN + n0 + ng + r * 32) * COUT + og + c * 8] = acc[r][c];
}

// ---------------------------------------------------------------------------
extern "C" void kernel_launch(void* const* d_in, const int* in_sizes, int n_in,
                              void* d_out, int out_size, void* d_ws, size_t ws_size,
                              hipStream_t stream) {
    const float* x   = (const float*)d_in[0];
    const float* adj = (const float*)d_in[1];
    const float* Ws  = (const float*)d_in[2];
    const float* bs  = (const float*)d_in[3];
    const float* We  = (const float*)d_in[4];
    const float* be  = (const float*)d_in[5];
    float* out = (float*)d_out;

    const size_t HSZ = (size_t)PAIRS * NN * HID_;
    float* h0 = (float*)d_ws;
    float* h1 = h0 + HSZ;
    float* h2 = h1 + HSZ;
    float* h3 = h2 + HSZ;
    unsigned short* Asw = (unsigned short*)(h3 + HSZ);   // 256 MB, bf16 tiles

    k_conv<<<dim3(64, PAIRS), 256, 0, stream>>>(adj, Asw);
    k_h0  <<<dim3(64, 8),     256, 0, stream>>>(x, Ws, bs, h0);
    k_prop<<<dim3(4, PAIRS),  512, 0, stream>>>(Asw, h0, h0, h1);
    k_prop<<<dim3(4, PAIRS),  512, 0, stream>>>(Asw, h1, h0, h2);
    k_prop<<<dim3(4, PAIRS),  512, 0, stream>>>(Asw, h2, h0, h3);
    k_out <<<dim3(8, PAIRS),  256, 0, stream>>>(h0, h1, h2, h3, We, be, out);
}

// Round 3
// 951.401 us; speedup vs baseline: 1.1047x; 1.0065x over previous
//
#include <hip/hip_runtime.h>
#include <stdint.h>

#define ALPHA 0.05f
constexpr int B_   = 8;
constexpr int CIN  = 32;
constexpr int NN   = 1024;
constexpr int CC   = 16;
constexpr int HID_ = 20;
constexpr int COUT = 32;
constexpr int PAIRS = B_ * CC;   // 128

typedef __attribute__((ext_vector_type(8))) short bf8;   // 8 bf16 in 4 VGPRs
typedef __attribute__((ext_vector_type(4))) float f4;

__device__ inline unsigned short f2bf(float x) {
    union { float f; uint32_t u; } v; v.f = x;
    uint32_t u = v.u;
    u += 0x7fffu + ((u >> 16) & 1u);   // round-to-nearest-even
    return (unsigned short)(u >> 16);
}

constexpr int BSTR = 1032;   // Ht row stride in bf16 (516 words, %32 = 4)
constexpr int HTR  = 21;     // Ht rows: 20 h-dims + ones row (rows 21..31 unneeded)
constexpr int ATS  = 72;     // Atr row stride in bf16 (144 B: 16B-aligned rows,
                             // 36 words -> 8 disjoint 4-word bank windows = floor)

// ---------------------------------------------------------------------------
// K1: h0[pair][n][l] = sum_i x[b][i][n][c] * W_start[i][l] + b_start[l]
// ---------------------------------------------------------------------------
__global__ __launch_bounds__(256) void k_h0(const float* __restrict__ x,
                                            const float* __restrict__ Ws,
                                            const float* __restrict__ bs,
                                            float* __restrict__ h0) {
    int b = blockIdx.y, n0 = blockIdx.x * 16;
    __shared__ float xs[CIN * 16 * CC];   // [i][nl][c], 32 KB
    __shared__ float WsS[CIN * HID_];
    __shared__ float bsS[HID_];
    int t = threadIdx.x;

    #pragma unroll
    for (int j = 0; j < 8; j++) {
        int idx = t + j * 256;            // 0..2047
        int i = idx >> 6, f = idx & 63;
        ((float4*)xs)[idx] =
            ((const float4*)(x + ((size_t)(b * CIN + i) * NN + n0) * CC))[f];
    }
    for (int j = t; j < CIN * HID_; j += 256) WsS[j] = Ws[j];
    if (t < HID_) bsS[t] = bs[t];
    __syncthreads();

    int c = t & 15, nl = t >> 4;
    float acc[HID_];
    #pragma unroll
    for (int l = 0; l < HID_; l++) acc[l] = bsS[l];
    for (int i = 0; i < CIN; i++) {
        float xv = xs[i * 256 + nl * 16 + c];
        #pragma unroll
        for (int l = 0; l < HID_; l++) acc[l] += xv * WsS[i * HID_ + l];
    }
    float* dst = h0 + ((size_t)(b * CC + c) * NN + (n0 + nl)) * HID_;
    #pragma unroll
    for (int l = 0; l < HID_; l++) dst[l] = acc[l];
}

// ---------------------------------------------------------------------------
// P1f: fused convert + first propagation.
//   Reads adj f32 COALESCED (wave-private 32x64 chunks, 256B bursts/row),
//   converts to bf16 through a wave-private LDS tile (no block barriers in
//   the K-loop), feeds MFMA A-frags AND stores them to Asw (contiguous 1 KB
//   per instr) for props 2/3.  h_out = ALPHA*h0 + (1-ALPHA)*(u + h0)/s.
//   grid: (4 m-tiles of 256, 128 pairs), block 512 (8 waves).
// ---------------------------------------------------------------------------
__global__ __launch_bounds__(512, 4) void k_prop1f(
        const float* __restrict__ adj,
        const float* __restrict__ h0g,
        float* __restrict__ h_out,
        unsigned short* __restrict__ Asw) {
    int pair = blockIdx.y, bx = blockIdx.x;
    int m0 = bx * 256;
    __shared__ unsigned short Ht[HTR * BSTR];    // 43.3 KB
    __shared__ unsigned short Atr[8][32 * ATS];  // 36.0 KB, wave-private tiles
    int t = threadIdx.x;
    int lane = t & 63, wave = t >> 6;
    int ml = lane & 15, quad = lane >> 4;

    // ---- stage B^T rows 0..19 = h0^T, row 20 = ones (rows >20 not needed) ----
    const float* hp = h0g + (size_t)pair * NN * HID_;
    for (int k = t; k < NN; k += 512) {
        float4 v0 = *(const float4*)(hp + (size_t)k * HID_ + 0);
        float4 v1 = *(const float4*)(hp + (size_t)k * HID_ + 4);
        float4 v2 = *(const float4*)(hp + (size_t)k * HID_ + 8);
        float4 v3 = *(const float4*)(hp + (size_t)k * HID_ + 12);
        float4 v4 = *(const float4*)(hp + (size_t)k * HID_ + 16);
        float vv[20] = {v0.x, v0.y, v0.z, v0.w, v1.x, v1.y, v1.z, v1.w,
                        v2.x, v2.y, v2.z, v2.w, v3.x, v3.y, v3.z, v3.w,
                        v4.x, v4.y, v4.z, v4.w};
        #pragma unroll
        for (int l = 0; l < HID_; l++) Ht[l * BSTR + k] = f2bf(vv[l]);
    }
    {   // ones row (row 20)
        uint4 ones; ones.x = ones.y = ones.z = ones.w = 0x3F803F80u;
        for (int idx = t; idx < NN / 8; idx += 512)
            *(uint4*)&Ht[20 * BSTR + idx * 8] = ones;
    }
    __syncthreads();

    // ---- K-loop: coalesced adj read -> LDS -> frags -> MFMA + Asw store ----
    f4 acc[2][2];
    #pragma unroll
    for (int mt = 0; mt < 2; mt++)
        #pragma unroll
        for (int nt = 0; nt < 2; nt++)
            #pragma unroll
            for (int r = 0; r < 4; r++) acc[mt][nt][r] = 0.0f;

    const float* ap = adj + ((size_t)pair * NN + m0 + wave * 32) * NN;
    unsigned short* AtrW = &Atr[wave][0];
    const int b0off = ml * BSTR + quad * 8;
    const int b1off = ((16 + ml <= 20) ? (16 + ml) : 20) * BSTR + quad * 8;
    unsigned short* aswp = Asw +
        ((size_t)pair * 64 + bx * 16 + wave * 2) * (32 * 512) + lane * 8;

    #pragma unroll 1
    for (int ks = 0; ks < NN; ks += 64) {
        // coalesced load: instr q covers rows 4q+quad, cols ml*4..+3 (256B bursts)
        float4 v[8];
        #pragma unroll
        for (int q = 0; q < 8; q++)
            v[q] = *(const float4*)(ap + (size_t)(q * 4 + quad) * NN + ks + ml * 4);
        // convert + wave-private LDS write (row-major [32][ATS])
        #pragma unroll
        for (int q = 0; q < 8; q++) {
            ushort4 w;
            w.x = f2bf(v[q].x); w.y = f2bf(v[q].y);
            w.z = f2bf(v[q].z); w.w = f2bf(v[q].w);
            *(ushort4*)&AtrW[(q * 4 + quad) * ATS + ml * 4] = w;
        }
        // frags + MFMA + Asw store
        #pragma unroll
        for (int kb = 0; kb < 2; kb++) {
            bf8 b0 = *(const bf8*)&Ht[b0off + ks + kb * 32];
            bf8 b1 = *(const bf8*)&Ht[b1off + ks + kb * 32];
            #pragma unroll
            for (int mt = 0; mt < 2; mt++) {
                bf8 a = *(const bf8*)&AtrW[(mt * 16 + ml) * ATS + kb * 32 + quad * 8];
                acc[mt][0] = __builtin_amdgcn_mfma_f32_16x16x32_bf16(a, b0, acc[mt][0], 0, 0, 0);
                acc[mt][1] = __builtin_amdgcn_mfma_f32_16x16x32_bf16(a, b1, acc[mt][1], 0, 0, 0);
                *(bf8*)(aswp + (size_t)(mt * 32 + (ks >> 5) + kb) * 512) = a;
            }
        }
    }

    // ---- epilogue (h_in == h0 here): col = lane&15 (+16*nt), row = quad*4+r ----
    #pragma unroll
    for (int mt = 0; mt < 2; mt++) {
        #pragma unroll
        for (int r = 0; r < 4; r++) {
            int row = m0 + wave * 32 + mt * 16 + quad * 4 + r;
            float s = __shfl(acc[mt][1][r], (quad << 4) + 4, 64) + 1.0f;
            float inv_s = (1.0f - ALPHA) / s;
            {
                size_t off = ((size_t)pair * NN + row) * HID_ + ml;
                float h0v = h0g[off];
                h_out[off] = ALPHA * h0v + inv_s * (acc[mt][0][r] + h0v);
            }
            if (ml < 4) {
                size_t off = ((size_t)pair * NN + row) * HID_ + 16 + ml;
                float h0v = h0g[off];
                h_out[off] = ALPHA * h0v + inv_s * (acc[mt][1][r] + h0v);
            }
        }
    }
}

// ---------------------------------------------------------------------------
// P: propagation from pre-swizzled bf16 A (props 2 and 3). Barrier-free
//    K-loop, register ping-pong prefetch, contiguous 1 KB frag loads.
// ---------------------------------------------------------------------------
__global__ __launch_bounds__(512, 4) void k_prop(
        const unsigned short* __restrict__ Asw,  // bf16 fragment-ordered A
        const float* __restrict__ h_in,   // f32: B source AND identity add
        const float* __restrict__ h0,     // f32: alpha mix
        float* __restrict__ h_out) {
    int pair = blockIdx.y;
    int m0 = blockIdx.x * 256;
    __shared__ unsigned short Ht[HTR * BSTR];   // 43.3 KB
    int t = threadIdx.x;
    int lane = t & 63, wave = t >> 6;
    int ml = lane & 15, quad = lane >> 4;

    // ---- stage B^T (once): rows 0..19 = h^T, row 20 = ones ----
    const float* hp = h_in + (size_t)pair * NN * HID_;
    for (int k = t; k < NN; k += 512) {
        float4 v0 = *(const float4*)(hp + (size_t)k * HID_ + 0);
        float4 v1 = *(const float4*)(hp + (size_t)k * HID_ + 4);
        float4 v2 = *(const float4*)(hp + (size_t)k * HID_ + 8);
        float4 v3 = *(const float4*)(hp + (size_t)k * HID_ + 12);
        float4 v4 = *(const float4*)(hp + (size_t)k * HID_ + 16);
        float vv[20] = {v0.x, v0.y, v0.z, v0.w, v1.x, v1.y, v1.z, v1.w,
                        v2.x, v2.y, v2.z, v2.w, v3.x, v3.y, v3.z, v3.w,
                        v4.x, v4.y, v4.z, v4.w};
        #pragma unroll
        for (int l = 0; l < HID_; l++) Ht[l * BSTR + k] = f2bf(vv[l]);
    }
    {   // ones row
        uint4 ones; ones.x = ones.y = ones.z = ones.w = 0x3F803F80u;
        for (int idx = t; idx < NN / 8; idx += 512)
            *(uint4*)&Ht[20 * BSTR + idx * 8] = ones;
    }
    __syncthreads();

    // ---- K-loop (no barriers) ----
    f4 acc[2][2];
    #pragma unroll
    for (int mt = 0; mt < 2; mt++)
        #pragma unroll
        for (int nt = 0; nt < 2; nt++)
            #pragma unroll
            for (int r = 0; r < 4; r++) acc[mt][nt][r] = 0.0f;

    const unsigned short* At0 = Asw +
        ((size_t)pair * 64 + blockIdx.x * 16 + wave * 2) * (32 * 512) + lane * 8;
    const unsigned short* At1 = At0 + 32 * 512;
    const int b0off = ml * BSTR + quad * 8;
    const int b1off = ((16 + ml <= 20) ? (16 + ml) : 20) * BSTR + quad * 8;

    bf8 cA0 = *(const bf8*)(At0);
    bf8 cA1 = *(const bf8*)(At1);
    bf8 cB0 = *(const bf8*)(At0 + 512);
    bf8 cB1 = *(const bf8*)(At1 + 512);

    #pragma unroll 1
    for (int ks = 0; ks < NN; ks += 64) {
        int kb = ks >> 5;
        int kn = (kb + 2 < 32) ? (kb + 2) : 0;   // wrap-guarded prefetch
        bf8 nA0 = *(const bf8*)(At0 + kn * 512);
        bf8 nA1 = *(const bf8*)(At1 + kn * 512);
        bf8 nB0 = *(const bf8*)(At0 + kn * 512 + 512);
        bf8 nB1 = *(const bf8*)(At1 + kn * 512 + 512);
        {
            bf8 b0 = *(const bf8*)&Ht[b0off + ks];
            bf8 b1 = *(const bf8*)&Ht[b1off + ks];
            acc[0][0] = __builtin_amdgcn_mfma_f32_16x16x32_bf16(cA0, b0, acc[0][0], 0, 0, 0);
            acc[0][1] = __builtin_amdgcn_mfma_f32_16x16x32_bf16(cA0, b1, acc[0][1], 0, 0, 0);
            acc[1][0] = __builtin_amdgcn_mfma_f32_16x16x32_bf16(cA1, b0, acc[1][0], 0, 0, 0);
            acc[1][1] = __builtin_amdgcn_mfma_f32_16x16x32_bf16(cA1, b1, acc[1][1], 0, 0, 0);
        }
        {
            bf8 b0 = *(const bf8*)&Ht[b0off + ks + 32];
            bf8 b1 = *(const bf8*)&Ht[b1off + ks + 32];
            acc[0][0] = __builtin_amdgcn_mfma_f32_16x16x32_bf16(cB0, b0, acc[0][0], 0, 0, 0);
            acc[0][1] = __builtin_amdgcn_mfma_f32_16x16x32_bf16(cB0, b1, acc[0][1], 0, 0, 0);
            acc[1][0] = __builtin_amdgcn_mfma_f32_16x16x32_bf16(cB1, b0, acc[1][0], 0, 0, 0);
            acc[1][1] = __builtin_amdgcn_mfma_f32_16x16x32_bf16(cB1, b1, acc[1][1], 0, 0, 0);
        }
        cA0 = nA0; cA1 = nA1; cB0 = nB0; cB1 = nB1;
    }

    // ---- epilogue ----
    #pragma unroll
    for (int mt = 0; mt < 2; mt++) {
        #pragma unroll
        for (int r = 0; r < 4; r++) {
            int row = m0 + wave * 32 + mt * 16 + quad * 4 + r;
            float s = __shfl(acc[mt][1][r], (quad << 4) + 4, 64) + 1.0f;
            float inv_s = (1.0f - ALPHA) / s;
            {
                size_t off = ((size_t)pair * NN + row) * HID_ + ml;
                h_out[off] = ALPHA * h0[off] + inv_s * (acc[mt][0][r] + h_in[off]);
            }
            if (ml < 4) {
                size_t off = ((size_t)pair * NN + row) * HID_ + 16 + ml;
                h_out[off] = ALPHA * h0[off] + inv_s * (acc[mt][1][r] + h_in[off]);
            }
        }
    }
}

// ---------------------------------------------------------------------------
// K3: out[pair][n][o] = sum_k [h0|h1|h2|h3][pair][n][k] * W_end[k][o] + b_end[o]
// ---------------------------------------------------------------------------
__global__ __launch_bounds__(256) void k_out(const float* __restrict__ h0,
                                             const float* __restrict__ h1,
                                             const float* __restrict__ h2,
                                             const float* __restrict__ h3,
                                             const float* __restrict__ We,
                                             const float* __restrict__ be,
                                             float* __restrict__ out) {
    int pair = blockIdx.y, n0 = blockIdx.x * 128;
    int t = threadIdx.x;
    __shared__ float WeT[32 * 84];   // WeT[o][k]
    __shared__ float beS[32];
    for (int idx = t; idx < 80 * 32; idx += 256) {
        int k = idx >> 5, o = idx & 31;
        WeT[o * 84 + k] = We[idx];
    }
    if (t < 32) beS[t] = be[t];
    __syncthreads();

    const float* hs[4] = {h0, h1, h2, h3};
    int og = t & 7, ng = t >> 3;
    float acc[4][4];
    #pragma unroll
    for (int r = 0; r < 4; r++)
        #pragma unroll
        for (int c = 0; c < 4; c++) acc[r][c] = beS[og + c * 8];

    #pragma unroll
    for (int src = 0; src < 4; src++) {
        const float* hp = hs[src] + ((size_t)pair * NN + n0 + ng) * HID_;
        #pragma unroll
        for (int j = 0; j < 5; j++) {
            float4 hv[4];
            #pragma unroll
            for (int r = 0; r < 4; r++)
                hv[r] = *(const float4*)(hp + (size_t)(r * 32) * HID_ + j * 4);
            #pragma unroll
            for (int c = 0; c < 4; c++) {
                float4 wv = *(const float4*)&WeT[(og + c * 8) * 84 + src * 20 + j * 4];
                #pragma unroll
                for (int r = 0; r < 4; r++)
                    acc[r][c] += hv[r].x * wv.x + hv[r].y * wv.y +
                                 hv[r].z * wv.z + hv[r].w * wv.w;
            }
        }
    }
    #pragma unroll
    for (int r = 0; r < 4; r++)
        #pragma unroll
        for (int c = 0; c < 4; c++)
            out[((size_t)pair * NN + n0 + ng + r * 32) * COUT + og + c * 8] = acc[r][c];
}

// ---------------------------------------------------------------------------
extern "C" void kernel_launch(void* const* d_in, const int* in_sizes, int n_in,
                              void* d_out, int out_size, void* d_ws, size_t ws_size,
                              hipStream_t stream) {
    const float* x   = (const float*)d_in[0];
    const float* adj = (const float*)d_in[1];
    const float* Ws  = (const float*)d_in[2];
    const float* bs  = (const float*)d_in[3];
    const float* We  = (const float*)d_in[4];
    const float* be  = (const float*)d_in[5];
    float* out = (float*)d_out;

    const size_t HSZ = (size_t)PAIRS * NN * HID_;
    float* h0 = (float*)d_ws;
    float* h1 = h0 + HSZ;
    float* h2 = h1 + HSZ;
    float* h3 = h2 + HSZ;
    unsigned short* Asw = (unsigned short*)(h3 + HSZ);   // 256 MB, bf16 frag tiles

    k_h0    <<<dim3(64, 8),    256, 0, stream>>>(x, Ws, bs, h0);
    k_prop1f<<<dim3(4, PAIRS), 512, 0, stream>>>(adj, h0, h1, Asw);
    k_prop  <<<dim3(4, PAIRS), 512, 0, stream>>>(Asw, h1, h0, h2);
    k_prop  <<<dim3(4, PAIRS), 512, 0, stream>>>(Asw, h2, h0, h3);
    k_out   <<<dim3(8, PAIRS), 256, 0, stream>>>(h0, h1, h2, h3, We, be, out);
}